// Round 14
// baseline (967.975 us; speedup 1.0000x reference)
//
#include <hip/hip_runtime.h>

typedef _Float16 f16;
typedef _Float16 f16x8 __attribute__((ext_vector_type(8)));
typedef _Float16 f16x4 __attribute__((ext_vector_type(4)));
typedef float    f32x4 __attribute__((ext_vector_type(4)));

#define B_SZ   2048
#define NCH    256
#define L0_    127
#define L1_    125
#define L2_    123
#define L3_    121
#define F1_    512
#define FCK    30976
#define KCH    968         // 30976 / 32 k-chunks
#define SPLIT  16          // split-K for FC1
#define KPS    61          // ceil(968/16); last split has 53

// async global->LDS, 16B per lane; dest = wave-uniform base + lane*16
__device__ __forceinline__ void gl16(const f16* g, f16* l) {
    __builtin_amdgcn_global_load_lds(
        (const __attribute__((address_space(1))) void*)g,
        (__attribute__((address_space(3))) void*)l, 16, 0, 0);
}

// ---------------------------------------------------------------------------
// preps (R12 verbatim)
// ---------------------------------------------------------------------------
__global__ __launch_bounds__(256) void prep_wpw(const float* __restrict__ Wp,
                                                f16* __restrict__ wpw) {
    int idx = blockIdx.x * 256 + threadIdx.x;
    if (idx >= NCH * 128) return;
    int c = idx >> 7, j = idx & 127;
    float v = (j < 64) ? Wp[c * 128 + j * 2 + 1] : Wp[c * 128 + (j - 64) * 2];
    wpw[idx] = (f16)v;
}

__global__ __launch_bounds__(256) void prep_wct3(const float* __restrict__ W1,
                                                 const float* __restrict__ W2,
                                                 const float* __restrict__ W3,
                                                 f16* __restrict__ wct1,
                                                 f16* __restrict__ wct2,
                                                 f16* __restrict__ wct3) {
    int g = blockIdx.x;
    const float* W = (g < 768) ? W1 : (g < 1536) ? W2 : W3;
    f16* dst = (g < 768) ? wct1 : (g < 1536) ? wct2 : wct3;
    int idx = (g % 768) * 256 + threadIdx.x;
    if (idx >= NCH * 768) return;
    int co = idx / 768, rem = idx - co * 768;
    int k = rem >> 8, ci = rem & 255;
    dst[idx] = (f16)W[((size_t)co * NCH + ci) * 3 + k];
}

__global__ __launch_bounds__(256) void prep_wf1k(const float* __restrict__ Wf1,
                                                 f16* __restrict__ wf1h) {
    __shared__ f16 t[NCH * 122];
    const int f = blockIdx.x, tid = threadIdx.x;
    const float* src = Wf1 + (size_t)f * FCK;
    for (int idx = tid; idx < FCK; idx += 256) {
        int co = idx / 121, l = idx - co * 121;
        t[co * 122 + l] = (f16)src[idx];
    }
    __syncthreads();
    f16* dst = wf1h + (size_t)f * FCK;
    for (int idx = tid; idx < FCK; idx += 256) {
        int l = idx >> 8, co = idx & 255;
        dst[idx] = t[co * 122 + l];
    }
}

__global__ __launch_bounds__(256) void prep_xh(const float* __restrict__ x,
                                               f16* __restrict__ xh) {
    size_t g = (size_t)blockIdx.x * 256 + threadIdx.x;
    size_t N = (size_t)B_SZ * 8192;
    if (g * 4 >= N + 64) return;
    if (g * 4 < N) {
        float4 v = *(const float4*)(x + g * 4);
        f16x4 h = { (f16)v.x, (f16)v.y, (f16)v.z, (f16)v.w };
        *(f16x4*)(xh + g * 4) = h;
    } else {
        f16x4 z = { (f16)0.f, (f16)0.f, (f16)0.f, (f16)0.f };
        *(f16x4*)(xh + g * 4) = z;
    }
}

// ---------------------------------------------------------------------------
// Conv / pointwise: R13 3-buffer staging + FRAG PREFETCH-1 (the R14 change).
// Per phase: stage(ks+2); vmcnt(2); barrier; ds_read frags for ks+1 into the
// OTHER frag set; lgkmcnt(8) (forces last step's reads done, new 8 in
// flight); MFMA on last step's frags; barrier.  MFMA depends on nothing
// issued this phase -> read/MFMA overlap across the SIMD's two waves.
// ---------------------------------------------------------------------------
#define READF(FA, FB, KS2)                                                    \
  {                                                                           \
    const int kn_ = (KS2) / CSTEPS, cbn_ = ((KS2) % CSTEPS) * 4;              \
    const int bufn_ = (KS2) % 3;                                              \
    _Pragma("unroll")                                                         \
    for (int m = 0; m < 4; ++m) {                                             \
      const int r_ = wl0 + 16 * m + lr + kn_;                                 \
      FA[m] = *(const f16x8*)(ins + r_ * CIN + (((cbn_ + lh) ^ (r_ & 7)) << 3)); \
    }                                                                         \
    _Pragma("unroll")                                                         \
    for (int n = 0; n < 4; ++n) {                                             \
      const int co_ = wc0 + 16 * n + lr;                                      \
      FB[n] = *(const f16x8*)(wlds + bufn_ * 8192                             \
                              + (co_ * 4 + (lh ^ ((co_ >> 2) & 3))) * 8);     \
    }                                                                         \
  }

#define PHASE(FCa, FCb, FNa, FNb, KS)                                         \
  {                                                                           \
    if ((KS) + 2 < KSTEPS) {                                                  \
      stageB((KS) + 2, ((KS) + 2) % 3);                                       \
      asm volatile("s_waitcnt vmcnt(2)" ::: "memory");                        \
    } else {                                                                  \
      asm volatile("s_waitcnt vmcnt(0)" ::: "memory");                        \
    }                                                                         \
    __builtin_amdgcn_sched_barrier(0);                                        \
    __builtin_amdgcn_s_barrier();                                             \
    __builtin_amdgcn_sched_barrier(0);                                        \
    if ((KS) + 1 < KSTEPS) {                                                  \
      READF(FNa, FNb, (KS) + 1)                                               \
      __builtin_amdgcn_sched_barrier(0);                                      \
      asm volatile("s_waitcnt lgkmcnt(8)" ::: "memory");                      \
    } else {                                                                  \
      asm volatile("s_waitcnt lgkmcnt(0)" ::: "memory");                      \
    }                                                                         \
    __builtin_amdgcn_sched_barrier(0);                                        \
    __builtin_amdgcn_s_setprio(1);                                            \
    _Pragma("unroll")                                                         \
    for (int n = 0; n < 4; ++n)                                               \
      _Pragma("unroll")                                                       \
      for (int m = 0; m < 4; ++m)                                             \
        acc[m][n] = __builtin_amdgcn_mfma_f32_16x16x32_f16(FCa[m], FCb[n],    \
                                                           acc[m][n], 0, 0, 0); \
    __builtin_amdgcn_s_setprio(0);                                            \
    __builtin_amdgcn_sched_barrier(0);                                        \
    __builtin_amdgcn_s_barrier();                                             \
  }

template <int KSTEPS, int CSTEPS, int UPR, int CIN, int SROWS, int LIN,
          int LOUT, bool ISPW>
__global__ __launch_bounds__(512) void convk(const f16* __restrict__ in,
                                             long in_bstride,
                                             const f16* __restrict__ wt,
                                             const float* __restrict__ bias,
                                             f16* __restrict__ out) {
    constexpr int KT = KSTEPS * 32;
    __shared__ f16 ins[SROWS * CIN];
    __shared__ f16 wlds[3 * 8192];          // 3 x (256co x 32k)

    const int b    = blockIdx.x;
    const int tid  = threadIdx.x;
    const int lane = tid & 63, w = tid >> 6;     // 8 waves
    const int wl0  = (w >> 2) * 64;              // 2 l-halves
    const int wc0  = (w & 3) * 64;               // 4 co-quarters
    const int lr   = lane & 15, lh = lane >> 4;
    const f16* inb = in + (size_t)b * in_bstride;

    auto stageB = [&](int ks, int buf) {
#pragma unroll
        for (int j = 0; j < 2; ++j) {
            int u = j * 512 + tid;
            int row = u >> 2, cu = u & 3;
            int cs = cu ^ ((row >> 2) & 3);
            gl16(wt + (size_t)row * KT + ks * 32 + cs * 8,
                 wlds + buf * 8192 + (size_t)(j * 512 + (w << 6)) * 8);
        }
    };

    stageB(0, 0);
    stageB(1, 1);
    for (int u = tid; u < SROWS * UPR; u += 512) {
        int r = u / UPR, sl = u % UPR;
        const f16* src;
        if (ISPW) {
            src = (sl < 8) ? inb + (size_t)r * 64 + sl * 8
                           : inb - 64 + (sl - 8) * 8;        // x0 block
        } else {
            int sr = (r < LIN) ? r : (LIN - 1);
            src = inb + (size_t)sr * NCH + sl * 8;
        }
        *(f16x8*)(ins + r * CIN + ((sl ^ (r & 7)) << 3)) = *(const f16x8*)src;
    }
    __syncthreads();                        // drains everything (once/block)

    f32x4 acc[4][4];
#pragma unroll
    for (int m = 0; m < 4; ++m)
#pragma unroll
        for (int n = 0; n < 4; ++n) acc[m][n] = (f32x4){0.f, 0.f, 0.f, 0.f};

    // prologue: frags for ks=0 (stage(0) complete via __syncthreads)
    f16x8 aC[4], bC[4], aN[4], bN[4];
    READF(aC, bC, 0)

#pragma unroll 1
    for (int ks = 0; ks < KSTEPS; ks += 2) {
        PHASE(aC, bC, aN, bN, ks)
        PHASE(aN, bN, aC, bC, ks + 1)
    }

    // epilogue: +bias, relu, fp16 store to [b][l][256]
    f16* ob = out + (size_t)b * LOUT * NCH;
#pragma unroll
    for (int n = 0; n < 4; ++n) {
        const int co = wc0 + 16 * n + lr;
        const float e = bias[co];
#pragma unroll
        for (int m = 0; m < 4; ++m)
#pragma unroll
            for (int r = 0; r < 4; ++r) {
                const int l = wl0 + 16 * m + lh * 4 + r;
                if (l < LOUT) {
                    float v = fmaxf(acc[m][n][r] + e, 0.f);
                    ob[(size_t)l * NCH + co] = (f16)v;
                }
            }
    }
}

// ---------------------------------------------------------------------------
// FC1 (R12 verbatim). Block tile 128b x 256f, 512 thr = 8 waves.
// ---------------------------------------------------------------------------
__global__ __launch_bounds__(512) void fc1k(const f16* __restrict__ A,
                                            const f16* __restrict__ Bw,
                                            float* __restrict__ part,
                                            int CB) {
    __shared__ f16 Asl[2 * 4096];
    __shared__ f16 Bsl[2 * 8192];
    const int m0 = blockIdx.x * 128, n0 = blockIdx.y * 256, sp = blockIdx.z;
    const int tid  = threadIdx.x;
    const int lane = tid & 63, w = tid >> 6;
    const int wb0  = (w >> 2) * 64, wf0 = (w & 3) * 64;
    const int lr   = lane & 15, lh = lane >> 4;
    const int ck0  = sp * KPS;
    const int kc   = min(KPS, KCH - ck0);

    auto stage = [&](int it, int buf) {
        const int k0 = (ck0 + it) * 32;
        {
            int u = tid;
            int row = u >> 2, cu = u & 3;
            int cs = cu ^ ((row >> 2) & 3);
            gl16(A + (size_t)(m0 + row) * FCK + k0 + cs * 8,
                 Asl + buf * 4096 + (w << 6) * 8);
        }
#pragma unroll
        for (int j = 0; j < 2; ++j) {
            int u = j * 512 + tid;
            int row = u >> 2, cu = u & 3;
            int cs = cu ^ ((row >> 2) & 3);
            gl16(Bw + (size_t)(n0 + row) * FCK + k0 + cs * 8,
                 Bsl + buf * 8192 + (j * 512 + (w << 6)) * 8);
        }
    };

    f32x4 acc[4][4];
#pragma unroll
    for (int m = 0; m < 4; ++m)
#pragma unroll
        for (int n = 0; n < 4; ++n) acc[m][n] = (f32x4){0.f, 0.f, 0.f, 0.f};

    stage(0, 0);
    __syncthreads();

#pragma unroll 1
    for (int it = 0; it < kc; ++it) {
        const int buf = it & 1;
        if (it + 1 < kc) {
            stage(it + 1, buf ^ 1);
            asm volatile("s_waitcnt vmcnt(3)" ::: "memory");
        } else {
            asm volatile("s_waitcnt vmcnt(0)" ::: "memory");
        }
        __builtin_amdgcn_sched_barrier(0);
        __builtin_amdgcn_s_barrier();
        __builtin_amdgcn_sched_barrier(0);

        f16x8 a[4], bf[4];
#pragma unroll
        for (int m = 0; m < 4; ++m) {
            const int row = wb0 + 16 * m + lr;
            a[m] = *(const f16x8*)(Asl + buf * 4096
                                   + (row * 4 + (lh ^ ((row >> 2) & 3))) * 8);
        }
#pragma unroll
        for (int n = 0; n < 4; ++n) {
            const int row = wf0 + 16 * n + lr;
            bf[n] = *(const f16x8*)(Bsl + buf * 8192
                                    + (row * 4 + (lh ^ ((row >> 2) & 3))) * 8);
        }
        __builtin_amdgcn_s_setprio(1);
#pragma unroll
        for (int m = 0; m < 4; ++m)
#pragma unroll
            for (int n = 0; n < 4; ++n)
                acc[m][n] = __builtin_amdgcn_mfma_f32_16x16x32_f16(
                    a[m], bf[n], acc[m][n], 0, 0, 0);
        __builtin_amdgcn_s_setprio(0);
        __builtin_amdgcn_sched_barrier(0);
        __builtin_amdgcn_s_barrier();
    }

#pragma unroll
    for (int m = 0; m < 4; ++m)
#pragma unroll
        for (int n = 0; n < 4; ++n)
#pragma unroll
            for (int r = 0; r < 4; ++r) {
                const int bl = m0 + wb0 + 16 * m + lh * 4 + r;
                const int f  = n0 + wf0 + 16 * n + lr;
                part[((size_t)sp * CB + bl) * F1_ + f] = acc[m][n][r];
            }
}

// h4[m,f] = relu(bf1[f] + sum_sp part[sp][m][f])  — float4-vectorized
__global__ __launch_bounds__(256) void fc1_reduce_kernel(const float* __restrict__ part,
                                                         const float* __restrict__ bf1,
                                                         float* __restrict__ h4,
                                                         int CB) {
    int idx4 = blockIdx.x * 256 + threadIdx.x;
    int f4 = (idx4 * 4) & (F1_ - 1);
    float4 s = *(const float4*)(bf1 + f4);
#pragma unroll
    for (int sp = 0; sp < SPLIT; ++sp) {
        float4 p = *(const float4*)(part + (size_t)sp * CB * F1_ + (size_t)idx4 * 4);
        s.x += p.x; s.y += p.y; s.z += p.z; s.w += p.w;
    }
    float4 o = { fmaxf(s.x, 0.f), fmaxf(s.y, 0.f), fmaxf(s.z, 0.f), fmaxf(s.w, 0.f) };
    *(float4*)(h4 + (size_t)idx4 * 4) = o;
}

// out[b] = bf2 + h4[b,:] . Wf2
__global__ __launch_bounds__(256) void fc2_kernel(const float* __restrict__ h4,
                                                  const float* __restrict__ Wf2,
                                                  const float* __restrict__ bf2,
                                                  float* __restrict__ out) {
    const int b    = blockIdx.x * 4 + (threadIdx.x >> 6);
    const int lane = threadIdx.x & 63;
    float s = 0.f;
#pragma unroll
    for (int i = 0; i < 8; ++i) s = fmaf(h4[(size_t)b * F1_ + lane + 64 * i],
                                         Wf2[lane + 64 * i], s);
#pragma unroll
    for (int o = 32; o > 0; o >>= 1) s += __shfl_xor(s, o);
    if (lane == 0) out[b] = s + bf2[0];
}

// ---------------------------------------------------------------------------
extern "C" void kernel_launch(void* const* d_in, const int* in_sizes, int n_in,
                              void* d_out, int out_size, void* d_ws, size_t ws_size,
                              hipStream_t stream) {
    const float* x   = (const float*)d_in[0];
    const float* Wp  = (const float*)d_in[1];
    const float* bp  = (const float*)d_in[2];
    const float* W1  = (const float*)d_in[3];
    const float* b1  = (const float*)d_in[4];
    const float* W2  = (const float*)d_in[5];
    const float* b2  = (const float*)d_in[6];
    const float* W3  = (const float*)d_in[7];
    const float* b3  = (const float*)d_in[8];
    const float* Wf1 = (const float*)d_in[9];
    const float* bf1 = (const float*)d_in[10];
    const float* Wf2 = (const float*)d_in[11];
    const float* bf2 = (const float*)d_in[12];
    float* out = (float*)d_out;

    // ---- workspace layout ----------------------------------------------
    char* base = (char*)d_ws;
    size_t off = 0;
    auto alloc = [&](size_t bytes) {
        size_t o = off; off = (off + bytes + 255) & ~(size_t)255; return o;
    };
    const size_t o_wpw  = alloc((size_t)NCH * 128 * 2);
    const size_t o_wct1 = alloc((size_t)NCH * 768 * 2);
    const size_t o_wct2 = alloc((size_t)NCH * 768 * 2);
    const size_t o_wct3 = alloc((size_t)NCH * 768 * 2);
    const size_t o_wf1h = alloc((size_t)F1_ * FCK * 2);
    const size_t o_xh   = alloc(((size_t)B_SZ * 8192 + 64) * 2);
    const size_t o_h4   = alloc((size_t)B_SZ * F1_ * 4);
    const size_t fixed  = off;

    int CB = 0;
    const int cand[5] = {2048, 1024, 512, 256, 128};
    for (int i = 0; i < 5; ++i) {
        size_t c = (size_t)cand[i];
        size_t need = fixed
            + (((size_t)SPLIT * c * F1_ * 4 + 255) & ~(size_t)255)   // part
            + ((c * (size_t)L0_ * NCH * 2 + 255) & ~(size_t)255)     // buf0
            + ((c * (size_t)L1_ * NCH * 2 + 255) & ~(size_t)255);    // buf1
        if (need <= ws_size) { CB = cand[i]; break; }
    }
    if (CB == 0) return;
    const int nchunk = B_SZ / CB;

    const size_t o_part = alloc((size_t)SPLIT * CB * F1_ * 4);
    const size_t o_buf0 = alloc((size_t)CB * L0_ * NCH * 2);
    const size_t o_buf1 = alloc((size_t)CB * L1_ * NCH * 2);

    f16*   wpw  = (f16*)(base + o_wpw);
    f16*   wct1 = (f16*)(base + o_wct1);
    f16*   wct2 = (f16*)(base + o_wct2);
    f16*   wct3 = (f16*)(base + o_wct3);
    f16*   wf1h = (f16*)(base + o_wf1h);
    f16*   xh   = (f16*)(base + o_xh);
    float* h4   = (float*)(base + o_h4);
    float* part = (float*)(base + o_part);
    f16*   buf0 = (f16*)(base + o_buf0);
    f16*   buf1 = (f16*)(base + o_buf1);

    // ---- preps ---------------------------------------------------------
    prep_wpw<<<128, 256, 0, stream>>>(Wp, wpw);
    prep_wct3<<<2304, 256, 0, stream>>>(W1, W2, W3, wct1, wct2, wct3);
    prep_wf1k<<<F1_, 256, 0, stream>>>(Wf1, wf1h);
    prep_xh<<<(int)((((size_t)B_SZ * 8192 + 64) / 4 + 255) / 256), 256, 0, stream>>>(x, xh);

    // ---- chunked pipeline ----------------------------------------------
    for (int c = 0; c < nchunk; ++c) {
        const size_t b0 = (size_t)c * CB;
        // pointwise as K=128 GEMM: in = xh[b][(l+1)*64..]; x0 at in-64
        convk<4, 4, 16, 128, 128, 128, L0_, true><<<CB, 512, 0, stream>>>(
            xh + b0 * 8192 + 64, 8192, wpw, bp, buf0);
        convk<24, 8, 32, 256, 130, L0_, L1_, false><<<CB, 512, 0, stream>>>(
            buf0, (long)L0_ * NCH, wct1, b1, buf1);
        convk<24, 8, 32, 256, 130, L1_, L2_, false><<<CB, 512, 0, stream>>>(
            buf1, (long)L1_ * NCH, wct2, b2, buf0);
        convk<24, 8, 32, 256, 130, L2_, L3_, false><<<CB, 512, 0, stream>>>(
            buf0, (long)L2_ * NCH, wct3, b3, buf1);
        // conv3 output [l][co] IS the FC1 A layout (wf1h K-permuted at prep)
        fc1k<<<dim3(CB / 128, 2, SPLIT), 512, 0, stream>>>(buf1, wf1h, part, CB);
        fc1_reduce_kernel<<<CB * F1_ / 1024, 256, 0, stream>>>(part, bf1,
                                                               h4 + b0 * F1_, CB);
    }

    fc2_kernel<<<B_SZ / 4, 256, 0, stream>>>(h4, Wf2, bf2, out);
}

// Round 15
// 918.613 us; speedup vs baseline: 1.0537x; 1.0537x over previous
//
#include <hip/hip_runtime.h>

typedef _Float16 f16;
typedef _Float16 f16x8 __attribute__((ext_vector_type(8)));
typedef _Float16 f16x4 __attribute__((ext_vector_type(4)));
typedef float    f32x4 __attribute__((ext_vector_type(4)));

#define B_SZ   2048
#define NCH    256
#define L0_    127
#define L1_    125
#define L2_    123
#define L3_    121
#define F1_    512
#define FCK    30976
#define KCH    968         // 30976 / 32 k-chunks
#define SPLIT  16          // split-K for FC1
#define KPS    61          // ceil(968/16); last split has 53

// async global->LDS, 16B per lane; dest = wave-uniform base + lane*16
__device__ __forceinline__ void gl16(const f16* g, f16* l) {
    __builtin_amdgcn_global_load_lds(
        (const __attribute__((address_space(1))) void*)g,
        (__attribute__((address_space(3))) void*)l, 16, 0, 0);
}

// ---------------------------------------------------------------------------
// merged weight prep: wpw (pointwise, [c][128]) + wct1..3 ([co][k*256+ci])
// ---------------------------------------------------------------------------
__global__ __launch_bounds__(256) void prep_w(const float* __restrict__ Wp,
                                              const float* __restrict__ W1,
                                              const float* __restrict__ W2,
                                              const float* __restrict__ W3,
                                              f16* __restrict__ wpw,
                                              f16* __restrict__ wct1,
                                              f16* __restrict__ wct2,
                                              f16* __restrict__ wct3) {
    int g = blockIdx.x;
    if (g < 128) {
        int idx = g * 256 + threadIdx.x;
        int c = idx >> 7, j = idx & 127;
        float v = (j < 64) ? Wp[c * 128 + j * 2 + 1]
                           : Wp[c * 128 + (j - 64) * 2];
        wpw[idx] = (f16)v;
        return;
    }
    int g2 = g - 128;
    const float* W = (g2 < 768) ? W1 : (g2 < 1536) ? W2 : W3;
    f16* dst = (g2 < 768) ? wct1 : (g2 < 1536) ? wct2 : wct3;
    int idx = (g2 % 768) * 256 + threadIdx.x;
    int co = idx / 768, rem = idx - co * 768;
    int k = rem >> 8, ci = rem & 255;
    dst[idx] = (f16)W[((size_t)co * NCH + ci) * 3 + k];
}

__global__ __launch_bounds__(256) void prep_wf1k(const float* __restrict__ Wf1,
                                                 f16* __restrict__ wf1h) {
    __shared__ f16 t[NCH * 122];
    const int f = blockIdx.x, tid = threadIdx.x;
    const float* src = Wf1 + (size_t)f * FCK;
    for (int idx = tid; idx < FCK; idx += 256) {
        int co = idx / 121, l = idx - co * 121;
        t[co * 122 + l] = (f16)src[idx];
    }
    __syncthreads();
    f16* dst = wf1h + (size_t)f * FCK;
    for (int idx = tid; idx < FCK; idx += 256) {
        int l = idx >> 8, co = idx & 255;
        dst[idx] = t[co * 122 + l];
    }
}

// ---------------------------------------------------------------------------
// Conv / pointwise: wave tile 128l x 64co (m=8, n=4) — R15 change.
// Block = one b, 256 thr = 4 waves (co quarters). A: [SROWS][CIN] LDS,
// XOR-swizzled, staged once (pointwise: staged directly from fp32 x).
// B: 3-buffer rotation via gl16, depth-2-in-flight counted vmcnt (8/4/0,
// 4 loads/thread/stage). Loop protocol identical to R13 (proven correct).
// ---------------------------------------------------------------------------
template <int KSTEPS, int CSTEPS, int UPR, int CIN, int SROWS, int LIN,
          int LOUT, bool ISPW>
__global__ __launch_bounds__(256) void convk(const f16* __restrict__ in,
                                             long in_bstride,
                                             const float* __restrict__ xin,
                                             const f16* __restrict__ wt,
                                             const float* __restrict__ bias,
                                             f16* __restrict__ out) {
    constexpr int KT = KSTEPS * 32;
    __shared__ f16 ins[SROWS * CIN];
    __shared__ f16 wlds[3 * 8192];          // 3 x (256co x 32k)

    const int b    = blockIdx.x;
    const int tid  = threadIdx.x;
    const int lane = tid & 63, w = tid >> 6;     // 4 waves
    const int wc0  = w * 64;                     // wave's 64-co quarter
    const int lr   = lane & 15, lh = lane >> 4;

    // stage B chunk `ks` into rotating buffer (4 gl16/thread)
    auto stageB = [&](int ks, int buf) {
#pragma unroll
        for (int j = 0; j < 4; ++j) {
            int u = j * 256 + tid;               // 16B unit id, 0..1023
            int row = u >> 2, cu = u & 3;
            int cs = cu ^ ((row >> 2) & 3);
            gl16(wt + (size_t)row * KT + ks * 32 + cs * 8,
                 wlds + buf * 8192 + (size_t)(j * 256 + (w << 6)) * 8);
        }
    };

    stageB(0, 0);
    stageB(1, 1);
    // stage A tile, XOR-swizzled (16B units, unit ^= row&7)
    if (ISPW) {
        const float* xr = xin + (size_t)b * 8192;
        for (int u = tid; u < SROWS * UPR; u += 256) {
            int r = u / UPR, sl = u % UPR;
            int off = (sl < 8) ? ((r + 1 < 128 ? (r + 1) * 64 : 127 * 64) + sl * 8)
                               : (sl - 8) * 8;   // x0 block
            float4 v0 = *(const float4*)(xr + off);
            float4 v1 = *(const float4*)(xr + off + 4);
            f16x8 h = { (f16)v0.x, (f16)v0.y, (f16)v0.z, (f16)v0.w,
                        (f16)v1.x, (f16)v1.y, (f16)v1.z, (f16)v1.w };
            *(f16x8*)(ins + r * CIN + ((sl ^ (r & 7)) << 3)) = h;
        }
    } else {
        const f16* inb = in + (size_t)b * in_bstride;
        for (int u = tid; u < SROWS * UPR; u += 256) {
            int r = u / UPR, sl = u % UPR;
            int sr = (r < LIN) ? r : (LIN - 1);
            *(f16x8*)(ins + r * CIN + ((sl ^ (r & 7)) << 3)) =
                *(const f16x8*)(inb + (size_t)sr * NCH + sl * 8);
        }
    }
    __syncthreads();                        // drains everything (once/block)

    f32x4 acc[8][4];
#pragma unroll
    for (int m = 0; m < 8; ++m)
#pragma unroll
        for (int n = 0; n < 4; ++n) acc[m][n] = (f32x4){0.f, 0.f, 0.f, 0.f};

#pragma unroll 1
    for (int ks = 0; ks < KSTEPS; ++ks) {
        const int rbuf = ks % 3;
        if (ks < KSTEPS - 2) {
            stageB(ks + 2, (ks + 2) % 3);
            asm volatile("s_waitcnt vmcnt(8)" ::: "memory");
        } else if (ks == KSTEPS - 2) {
            asm volatile("s_waitcnt vmcnt(4)" ::: "memory");
        } else {
            asm volatile("s_waitcnt vmcnt(0)" ::: "memory");
        }
        __builtin_amdgcn_sched_barrier(0);
        __builtin_amdgcn_s_barrier();
        __builtin_amdgcn_sched_barrier(0);

        const int k = ks / CSTEPS, cb = (ks % CSTEPS) * 4;
        f16x8 a[8], bf[4];
#pragma unroll
        for (int m = 0; m < 8; ++m) {
            const int r_ = 16 * m + lr + k;
            a[m] = *(const f16x8*)(ins + r_ * CIN + (((cb + lh) ^ (r_ & 7)) << 3));
        }
#pragma unroll
        for (int n = 0; n < 4; ++n) {
            const int co = wc0 + 16 * n + lr;
            bf[n] = *(const f16x8*)(wlds + rbuf * 8192
                                    + (co * 4 + (lh ^ ((co >> 2) & 3))) * 8);
        }
        __builtin_amdgcn_s_setprio(1);
#pragma unroll
        for (int n = 0; n < 4; ++n)
#pragma unroll
            for (int m = 0; m < 8; ++m)
                acc[m][n] = __builtin_amdgcn_mfma_f32_16x16x32_f16(
                    a[m], bf[n], acc[m][n], 0, 0, 0);
        __builtin_amdgcn_s_setprio(0);
        __builtin_amdgcn_sched_barrier(0);
        __builtin_amdgcn_s_barrier();
    }

    // epilogue: +bias, relu, fp16 store to [b][l][256]
    f16* ob = out + (size_t)b * LOUT * NCH;
#pragma unroll
    for (int n = 0; n < 4; ++n) {
        const int co = wc0 + 16 * n + lr;
        const float e = bias[co];
#pragma unroll
        for (int m = 0; m < 8; ++m)
#pragma unroll
            for (int r = 0; r < 4; ++r) {
                const int l = 16 * m + lh * 4 + r;
                if (l < LOUT) {
                    float v = fmaxf(acc[m][n][r] + e, 0.f);
                    ob[(size_t)l * NCH + co] = (f16)v;
                }
            }
    }
}

// ---------------------------------------------------------------------------
// FC1 (R12 verbatim). Block tile 128b x 256f, 512 thr = 8 waves.
// ---------------------------------------------------------------------------
__global__ __launch_bounds__(512) void fc1k(const f16* __restrict__ A,
                                            const f16* __restrict__ Bw,
                                            float* __restrict__ part,
                                            int CB) {
    __shared__ f16 Asl[2 * 4096];
    __shared__ f16 Bsl[2 * 8192];
    const int m0 = blockIdx.x * 128, n0 = blockIdx.y * 256, sp = blockIdx.z;
    const int tid  = threadIdx.x;
    const int lane = tid & 63, w = tid >> 6;
    const int wb0  = (w >> 2) * 64, wf0 = (w & 3) * 64;
    const int lr   = lane & 15, lh = lane >> 4;
    const int ck0  = sp * KPS;
    const int kc   = min(KPS, KCH - ck0);

    auto stage = [&](int it, int buf) {
        const int k0 = (ck0 + it) * 32;
        {
            int u = tid;
            int row = u >> 2, cu = u & 3;
            int cs = cu ^ ((row >> 2) & 3);
            gl16(A + (size_t)(m0 + row) * FCK + k0 + cs * 8,
                 Asl + buf * 4096 + (w << 6) * 8);
        }
#pragma unroll
        for (int j = 0; j < 2; ++j) {
            int u = j * 512 + tid;
            int row = u >> 2, cu = u & 3;
            int cs = cu ^ ((row >> 2) & 3);
            gl16(Bw + (size_t)(n0 + row) * FCK + k0 + cs * 8,
                 Bsl + buf * 8192 + (j * 512 + (w << 6)) * 8);
        }
    };

    f32x4 acc[4][4];
#pragma unroll
    for (int m = 0; m < 4; ++m)
#pragma unroll
        for (int n = 0; n < 4; ++n) acc[m][n] = (f32x4){0.f, 0.f, 0.f, 0.f};

    stage(0, 0);
    __syncthreads();

#pragma unroll 1
    for (int it = 0; it < kc; ++it) {
        const int buf = it & 1;
        if (it + 1 < kc) {
            stage(it + 1, buf ^ 1);
            asm volatile("s_waitcnt vmcnt(3)" ::: "memory");
        } else {
            asm volatile("s_waitcnt vmcnt(0)" ::: "memory");
        }
        __builtin_amdgcn_sched_barrier(0);
        __builtin_amdgcn_s_barrier();
        __builtin_amdgcn_sched_barrier(0);

        f16x8 a[4], bf[4];
#pragma unroll
        for (int m = 0; m < 4; ++m) {
            const int row = wb0 + 16 * m + lr;
            a[m] = *(const f16x8*)(Asl + buf * 4096
                                   + (row * 4 + (lh ^ ((row >> 2) & 3))) * 8);
        }
#pragma unroll
        for (int n = 0; n < 4; ++n) {
            const int row = wf0 + 16 * n + lr;
            bf[n] = *(const f16x8*)(Bsl + buf * 8192
                                    + (row * 4 + (lh ^ ((row >> 2) & 3))) * 8);
        }
        __builtin_amdgcn_s_setprio(1);
#pragma unroll
        for (int m = 0; m < 4; ++m)
#pragma unroll
            for (int n = 0; n < 4; ++n)
                acc[m][n] = __builtin_amdgcn_mfma_f32_16x16x32_f16(
                    a[m], bf[n], acc[m][n], 0, 0, 0);
        __builtin_amdgcn_s_setprio(0);
        __builtin_amdgcn_sched_barrier(0);
        __builtin_amdgcn_s_barrier();
    }

#pragma unroll
    for (int m = 0; m < 4; ++m)
#pragma unroll
        for (int n = 0; n < 4; ++n)
#pragma unroll
            for (int r = 0; r < 4; ++r) {
                const int bl = m0 + wb0 + 16 * m + lh * 4 + r;
                const int f  = n0 + wf0 + 16 * n + lr;
                part[((size_t)sp * CB + bl) * F1_ + f] = acc[m][n][r];
            }
}

// ---------------------------------------------------------------------------
// fused reduce + fc2: out[b] = bf2 + relu(bf1 + sum_sp part)[.] . Wf2
// Block = one chunk-local b, 512 threads (thread = f).
// ---------------------------------------------------------------------------
__global__ __launch_bounds__(512) void fcout(const float* __restrict__ part,
                                             const float* __restrict__ bf1,
                                             const float* __restrict__ Wf2,
                                             const float* __restrict__ bf2,
                                             float* __restrict__ out,
                                             int CB) {
    __shared__ float red[8];
    const int m = blockIdx.x;
    const int f = threadIdx.x;
    float s = bf1[f];
#pragma unroll
    for (int sp = 0; sp < SPLIT; ++sp)
        s += part[((size_t)sp * CB + m) * F1_ + f];
    float p = fmaxf(s, 0.f) * Wf2[f];
#pragma unroll
    for (int o = 32; o > 0; o >>= 1) p += __shfl_xor(p, o);
    if ((f & 63) == 0) red[f >> 6] = p;
    __syncthreads();
    if (f < 8) {
        float v = red[f];
        v += __shfl_xor(v, 1);
        v += __shfl_xor(v, 2);
        v += __shfl_xor(v, 4);
        if (f == 0) out[m] = v + bf2[0];
    }
}

// ---------------------------------------------------------------------------
extern "C" void kernel_launch(void* const* d_in, const int* in_sizes, int n_in,
                              void* d_out, int out_size, void* d_ws, size_t ws_size,
                              hipStream_t stream) {
    const float* x   = (const float*)d_in[0];
    const float* Wp  = (const float*)d_in[1];
    const float* bp  = (const float*)d_in[2];
    const float* W1  = (const float*)d_in[3];
    const float* b1  = (const float*)d_in[4];
    const float* W2  = (const float*)d_in[5];
    const float* b2  = (const float*)d_in[6];
    const float* W3  = (const float*)d_in[7];
    const float* b3  = (const float*)d_in[8];
    const float* Wf1 = (const float*)d_in[9];
    const float* bf1 = (const float*)d_in[10];
    const float* Wf2 = (const float*)d_in[11];
    const float* bf2 = (const float*)d_in[12];
    float* out = (float*)d_out;

    // ---- workspace layout ----------------------------------------------
    char* base = (char*)d_ws;
    size_t off = 0;
    auto alloc = [&](size_t bytes) {
        size_t o = off; off = (off + bytes + 255) & ~(size_t)255; return o;
    };
    const size_t o_wpw  = alloc((size_t)NCH * 128 * 2);
    const size_t o_wct1 = alloc((size_t)NCH * 768 * 2);
    const size_t o_wct2 = alloc((size_t)NCH * 768 * 2);
    const size_t o_wct3 = alloc((size_t)NCH * 768 * 2);
    const size_t o_wf1h = alloc((size_t)F1_ * FCK * 2);
    const size_t fixed  = off;

    int CB = 0;
    const int cand[5] = {2048, 1024, 512, 256, 128};
    for (int i = 0; i < 5; ++i) {
        size_t c = (size_t)cand[i];
        size_t need = fixed
            + (((size_t)SPLIT * c * F1_ * 4 + 255) & ~(size_t)255)   // part
            + ((c * (size_t)L0_ * NCH * 2 + 255) & ~(size_t)255)     // buf0
            + ((c * (size_t)L1_ * NCH * 2 + 255) & ~(size_t)255);    // buf1
        if (need <= ws_size) { CB = cand[i]; break; }
    }
    if (CB == 0) return;
    const int nchunk = B_SZ / CB;

    const size_t o_part = alloc((size_t)SPLIT * CB * F1_ * 4);
    const size_t o_buf0 = alloc((size_t)CB * L0_ * NCH * 2);
    const size_t o_buf1 = alloc((size_t)CB * L1_ * NCH * 2);

    f16*   wpw  = (f16*)(base + o_wpw);
    f16*   wct1 = (f16*)(base + o_wct1);
    f16*   wct2 = (f16*)(base + o_wct2);
    f16*   wct3 = (f16*)(base + o_wct3);
    f16*   wf1h = (f16*)(base + o_wf1h);
    float* part = (float*)(base + o_part);
    f16*   buf0 = (f16*)(base + o_buf0);
    f16*   buf1 = (f16*)(base + o_buf1);

    // ---- preps ---------------------------------------------------------
    prep_w<<<2432, 256, 0, stream>>>(Wp, W1, W2, W3, wpw, wct1, wct2, wct3);
    prep_wf1k<<<F1_, 256, 0, stream>>>(Wf1, wf1h);

    // ---- chunked pipeline ----------------------------------------------
    for (int c = 0; c < nchunk; ++c) {
        const size_t b0 = (size_t)c * CB;
        // pointwise as K=128 GEMM, staging converts fp32 x in-kernel
        convk<4, 4, 16, 128, 128, 128, L0_, true><<<CB, 256, 0, stream>>>(
            nullptr, 0, x + b0 * 8192, wpw, bp, buf0);
        convk<24, 8, 32, 256, 130, L0_, L1_, false><<<CB, 256, 0, stream>>>(
            buf0, (long)L0_ * NCH, nullptr, wct1, b1, buf1);
        convk<24, 8, 32, 256, 130, L1_, L2_, false><<<CB, 256, 0, stream>>>(
            buf1, (long)L1_ * NCH, nullptr, wct2, b2, buf0);
        convk<24, 8, 32, 256, 130, L2_, L3_, false><<<CB, 256, 0, stream>>>(
            buf0, (long)L2_ * NCH, nullptr, wct3, b3, buf1);
        // conv3 output [l][co] IS the FC1 A layout (wf1h K-permuted at prep)
        fc1k<<<dim3(CB / 128, 2, SPLIT), 512, 0, stream>>>(buf1, wf1h, part, CB);
        fcout<<<CB, 512, 0, stream>>>(part, bf1, Wf2, bf2, out + b0, CB);
    }
}

// Round 16
// 854.162 us; speedup vs baseline: 1.1332x; 1.0755x over previous
//
#include <hip/hip_runtime.h>

typedef _Float16 f16;
typedef _Float16 f16x8 __attribute__((ext_vector_type(8)));
typedef _Float16 f16x4 __attribute__((ext_vector_type(4)));
typedef float    f32x4 __attribute__((ext_vector_type(4)));

#define B_SZ   2048
#define NCH    256
#define L0_    127
#define L1_    125
#define L2_    123
#define L3_    121
#define F1_    512
#define FCK    30976
#define KCH    968         // 30976 / 32 k-chunks
#define SPLIT  22          // split-K for FC1: 968 = 22 * 44 exactly
#define KPS    44          // 32-chunks per split = 22 BK-64 steps
#define NS_FC  22

// async global->LDS, 16B per lane; dest = wave-uniform base + lane*16
__device__ __forceinline__ void gl16(const f16* g, f16* l) {
    __builtin_amdgcn_global_load_lds(
        (const __attribute__((address_space(1))) void*)g,
        (__attribute__((address_space(3))) void*)l, 16, 0, 0);
}

// ---------------------------------------------------------------------------
// merged weight prep, CHUNK-MAJOR [ks32][co][32] (coalesced staging):
// wpw: 4 chunks (K=128: [wp1 | wp0]); wct1..3: 24 chunks (kt = k*256+ci)
// ---------------------------------------------------------------------------
__global__ __launch_bounds__(256) void prep_w(const float* __restrict__ Wp,
                                              const float* __restrict__ W1,
                                              const float* __restrict__ W2,
                                              const float* __restrict__ W3,
                                              f16* __restrict__ wpw,
                                              f16* __restrict__ wct1,
                                              f16* __restrict__ wct2,
                                              f16* __restrict__ wct3) {
    int g = blockIdx.x;
    if (g < 128) {
        int idx = g * 256 + threadIdx.x;        // [ck][co][w5]
        int ck = idx >> 13, co = (idx >> 5) & 255, w5 = idx & 31;
        int j = ck * 32 + w5;                   // ci 0..127
        float v = (j < 64) ? Wp[co * 128 + j * 2 + 1]
                           : Wp[co * 128 + (j - 64) * 2];
        wpw[idx] = (f16)v;
        return;
    }
    int g2 = g - 128;
    const float* W = (g2 < 768) ? W1 : (g2 < 1536) ? W2 : W3;
    f16* dst = (g2 < 768) ? wct1 : (g2 < 1536) ? wct2 : wct3;
    int idx = (g2 % 768) * 256 + threadIdx.x;   // [ck][co][w5]
    int ck = idx >> 13, co = (idx >> 5) & 255, w5 = idx & 31;
    int kt = ck * 32 + w5;
    int k = kt >> 8, ci = kt & 255;
    dst[idx] = (f16)W[((size_t)co * NCH + ci) * 3 + k];
}

__global__ __launch_bounds__(256) void prep_wf1k(const float* __restrict__ Wf1,
                                                 f16* __restrict__ wf1h) {
    __shared__ f16 t[NCH * 122];
    const int f = blockIdx.x, tid = threadIdx.x;
    const float* src = Wf1 + (size_t)f * FCK;
    for (int idx = tid; idx < FCK; idx += 256) {
        int co = idx / 121, l = idx - co * 121;
        t[co * 122 + l] = (f16)src[idx];
    }
    __syncthreads();
    f16* dst = wf1h + (size_t)f * FCK;
    for (int idx = tid; idx < FCK; idx += 256) {
        int l = idx >> 8, co = idx & 255;
        dst[idx] = t[co * 122 + l];
    }
}

// ---------------------------------------------------------------------------
// Conv / pointwise, BK=64 (the R16 change): NS steps of 2 x 32-chunks.
// Block = one b, 256 thr = 4 waves (co quarters), wave tile 128l x 64co.
// A: [SROWS][CIN] LDS, XOR-swizzled, staged once (pw: from fp32 x directly).
// B: 2-buffer LDS dbuf (16K f16 each) via gl16, chunk-major source.
// ONE barrier per step: stage(s+1)->cur^1 at top; reads of cur; MFMA x64;
// vmcnt(0); barrier.  In-flight window = full MFMA cluster (~1240cy).
// ---------------------------------------------------------------------------
template <int NS, int CSTEPS, int UPR, int CIN, int SROWS, int LIN,
          int LOUT, bool ISPW>
__global__ __launch_bounds__(256, 1) void convk(const f16* __restrict__ in,
                                                long in_bstride,
                                                const float* __restrict__ xin,
                                                const f16* __restrict__ wt,
                                                const float* __restrict__ bias,
                                                f16* __restrict__ out) {
    constexpr int BUFF = 16384;                  // f16 per B buffer (2 chunks)
    __shared__ f16 ins[SROWS * CIN];
    __shared__ f16 wlds[2 * BUFF];

    const int b    = blockIdx.x;
    const int tid  = threadIdx.x;
    const int lane = tid & 63, w = tid >> 6;     // 4 waves
    const int wc0  = w * 64;                     // wave's 64-co quarter
    const int lr   = lane & 15, lh = lane >> 4;

    // stage BK=64 pair s2 (chunks 2*s2, 2*s2+1): 8 gl16/thread, coalesced
    auto stageB = [&](int s2, int buf) {
        const f16* src0 = wt + (size_t)(2 * s2) * 8192;
#pragma unroll
        for (int j = 0; j < 8; ++j) {
            int u = j * 256 + w * 64 + lane;     // 16B unit, 0..2047
            int row = u >> 2, cu = u & 3;        // row 0..511 spans both chunks
            int cs = cu ^ ((row >> 2) & 3);
            gl16(src0 + row * 32 + cs * 8,
                 wlds + buf * BUFF + (size_t)(j * 256 + w * 64) * 8);
        }
    };

    stageB(0, 0);
    // stage A tile, XOR-swizzled (16B units, unit ^= row&7)
    if (ISPW) {
        const float* xr = xin + (size_t)b * 8192;
        for (int u = tid; u < SROWS * UPR; u += 256) {
            int r = u / UPR, sl = u % UPR;
            int off = (sl < 8) ? ((r + 1 < 128 ? (r + 1) * 64 : 127 * 64) + sl * 8)
                               : (sl - 8) * 8;   // x0 block
            float4 v0 = *(const float4*)(xr + off);
            float4 v1 = *(const float4*)(xr + off + 4);
            f16x8 h = { (f16)v0.x, (f16)v0.y, (f16)v0.z, (f16)v0.w,
                        (f16)v1.x, (f16)v1.y, (f16)v1.z, (f16)v1.w };
            *(f16x8*)(ins + r * CIN + ((sl ^ (r & 7)) << 3)) = h;
        }
    } else {
        const f16* inb = in + (size_t)b * in_bstride;
        for (int u = tid; u < SROWS * UPR; u += 256) {
            int r = u / UPR, sl = u % UPR;
            int sr = (r < LIN) ? r : (LIN - 1);
            *(f16x8*)(ins + r * CIN + ((sl ^ (r & 7)) << 3)) =
                *(const f16x8*)(inb + (size_t)sr * NCH + sl * 8);
        }
    }
    __syncthreads();                             // drains all prologue vmem

    f32x4 acc[8][4];
#pragma unroll
    for (int m = 0; m < 8; ++m)
#pragma unroll
        for (int n = 0; n < 4; ++n) acc[m][n] = (f32x4){0.f, 0.f, 0.f, 0.f};

#pragma unroll 1
    for (int s = 0; s < NS; ++s) {
        const int cur = s & 1;
        if (s + 1 < NS) stageB(s + 1, cur ^ 1);
        __builtin_amdgcn_sched_barrier(0);
#pragma unroll
        for (int kk = 0; kk < 2; ++kk) {
            const int ks32 = 2 * s + kk;
            const int k = ks32 / CSTEPS, cb = (ks32 % CSTEPS) * 4;
            f16x8 a[8], bf[4];
#pragma unroll
            for (int m = 0; m < 8; ++m) {
                const int r_ = 16 * m + lr + k;
                a[m] = *(const f16x8*)(ins + r_ * CIN
                                       + (((cb + lh) ^ (r_ & 7)) << 3));
            }
#pragma unroll
            for (int n = 0; n < 4; ++n) {
                const int co = wc0 + 16 * n + lr;
                bf[n] = *(const f16x8*)(wlds + cur * BUFF + kk * 8192
                                        + (co * 4 + (lh ^ ((co >> 2) & 3))) * 8);
            }
            __builtin_amdgcn_s_setprio(1);
#pragma unroll
            for (int n = 0; n < 4; ++n)
#pragma unroll
                for (int m = 0; m < 8; ++m)
                    acc[m][n] = __builtin_amdgcn_mfma_f32_16x16x32_f16(
                        a[m], bf[n], acc[m][n], 0, 0, 0);
            __builtin_amdgcn_s_setprio(0);
        }
        __builtin_amdgcn_sched_barrier(0);
        asm volatile("s_waitcnt vmcnt(0)" ::: "memory");
        __builtin_amdgcn_sched_barrier(0);
        __builtin_amdgcn_s_barrier();
    }

    // epilogue: +bias, relu, fp16 store to [b][l][256]
    f16* ob = out + (size_t)b * LOUT * NCH;
#pragma unroll
    for (int n = 0; n < 4; ++n) {
        const int co = wc0 + 16 * n + lr;
        const float e = bias[co];
#pragma unroll
        for (int m = 0; m < 8; ++m)
#pragma unroll
            for (int r = 0; r < 4; ++r) {
                const int l = 16 * m + lh * 4 + r;
                if (l < LOUT) {
                    float v = fmaxf(acc[m][n][r] + e, 0.f);
                    ob[(size_t)l * NCH + co] = (f16)v;
                }
            }
    }
}

// ---------------------------------------------------------------------------
// FC1, BK=64: tile 128b x 256f, 512 thr = 8 waves (2x4 of 64x64).
// A(16KB)+B(32KB) double-buffered via gl16 (row-major source, 64-col slice,
// XOR swizzle over 8 units/row).  One barrier per step, 22 steps/split.
// ---------------------------------------------------------------------------
__global__ __launch_bounds__(512, 1) void fc1k(const f16* __restrict__ A,
                                               const f16* __restrict__ Bw,
                                               float* __restrict__ part,
                                               int CB) {
    __shared__ f16 Asl[2 * 8192];                // 2 x (128b x 64k)
    __shared__ f16 Bsl[2 * 16384];               // 2 x (256f x 64k)
    const int m0 = blockIdx.x * 128, n0 = blockIdx.y * 256, sp = blockIdx.z;
    const int tid  = threadIdx.x;
    const int lane = tid & 63, w = tid >> 6;
    const int wb0  = (w >> 2) * 64, wf0 = (w & 3) * 64;
    const int lr   = lane & 15, lh = lane >> 4;
    const int ck0  = sp * KPS;

    auto stage = [&](int s2, int buf) {
        const int k0 = (ck0 + 2 * s2) * 32;      // f16 col base, 64 wide
#pragma unroll
        for (int j = 0; j < 2; ++j) {            // A: 1024 units
            int u = j * 512 + tid;
            int row = u >> 3, cu = u & 7;
            int cs = cu ^ (row & 7);
            gl16(A + (size_t)(m0 + row) * FCK + k0 + cs * 8,
                 Asl + buf * 8192 + (size_t)(j * 512 + w * 64) * 8);
        }
#pragma unroll
        for (int j = 0; j < 4; ++j) {            // B: 2048 units
            int u = j * 512 + tid;
            int row = u >> 3, cu = u & 7;
            int cs = cu ^ (row & 7);
            gl16(Bw + (size_t)(n0 + row) * FCK + k0 + cs * 8,
                 Bsl + buf * 16384 + (size_t)(j * 512 + w * 64) * 8);
        }
    };

    f32x4 acc[4][4];
#pragma unroll
    for (int m = 0; m < 4; ++m)
#pragma unroll
        for (int n = 0; n < 4; ++n) acc[m][n] = (f32x4){0.f, 0.f, 0.f, 0.f};

    stage(0, 0);
    __syncthreads();

#pragma unroll 1
    for (int s = 0; s < NS_FC; ++s) {
        const int cur = s & 1;
        if (s + 1 < NS_FC) stage(s + 1, cur ^ 1);
        __builtin_amdgcn_sched_barrier(0);
#pragma unroll
        for (int kk = 0; kk < 2; ++kk) {
            f16x8 a[4], bf[4];
#pragma unroll
            for (int m = 0; m < 4; ++m) {
                const int row = wb0 + 16 * m + lr;
                const int un = (kk * 4 + lh) ^ (row & 7);
                a[m] = *(const f16x8*)(Asl + cur * 8192 + row * 64 + un * 8);
            }
#pragma unroll
            for (int n = 0; n < 4; ++n) {
                const int row = wf0 + 16 * n + lr;
                const int un = (kk * 4 + lh) ^ (row & 7);
                bf[n] = *(const f16x8*)(Bsl + cur * 16384 + row * 64 + un * 8);
            }
            __builtin_amdgcn_s_setprio(1);
#pragma unroll
            for (int m = 0; m < 4; ++m)
#pragma unroll
                for (int n = 0; n < 4; ++n)
                    acc[m][n] = __builtin_amdgcn_mfma_f32_16x16x32_f16(
                        a[m], bf[n], acc[m][n], 0, 0, 0);
            __builtin_amdgcn_s_setprio(0);
        }
        __builtin_amdgcn_sched_barrier(0);
        asm volatile("s_waitcnt vmcnt(0)" ::: "memory");
        __builtin_amdgcn_sched_barrier(0);
        __builtin_amdgcn_s_barrier();
    }

#pragma unroll
    for (int m = 0; m < 4; ++m)
#pragma unroll
        for (int n = 0; n < 4; ++n)
#pragma unroll
            for (int r = 0; r < 4; ++r) {
                const int bl = m0 + wb0 + 16 * m + lh * 4 + r;
                const int f  = n0 + wf0 + 16 * n + lr;
                part[((size_t)sp * CB + bl) * F1_ + f] = acc[m][n][r];
            }
}

// ---------------------------------------------------------------------------
// fused reduce + fc2: out[b] = bf2 + relu(bf1 + sum_sp part)[.] . Wf2
// ---------------------------------------------------------------------------
__global__ __launch_bounds__(512) void fcout(const float* __restrict__ part,
                                             const float* __restrict__ bf1,
                                             const float* __restrict__ Wf2,
                                             const float* __restrict__ bf2,
                                             float* __restrict__ out,
                                             int CB) {
    __shared__ float red[8];
    const int m = blockIdx.x;
    const int f = threadIdx.x;
    float s = bf1[f];
#pragma unroll
    for (int sp = 0; sp < SPLIT; ++sp)
        s += part[((size_t)sp * CB + m) * F1_ + f];
    float p = fmaxf(s, 0.f) * Wf2[f];
#pragma unroll
    for (int o = 32; o > 0; o >>= 1) p += __shfl_xor(p, o);
    if ((f & 63) == 0) red[f >> 6] = p;
    __syncthreads();
    if (f < 8) {
        float v = red[f];
        v += __shfl_xor(v, 1);
        v += __shfl_xor(v, 2);
        v += __shfl_xor(v, 4);
        if (f == 0) out[m] = v + bf2[0];
    }
}

// ---------------------------------------------------------------------------
extern "C" void kernel_launch(void* const* d_in, const int* in_sizes, int n_in,
                              void* d_out, int out_size, void* d_ws, size_t ws_size,
                              hipStream_t stream) {
    const float* x   = (const float*)d_in[0];
    const float* Wp  = (const float*)d_in[1];
    const float* bp  = (const float*)d_in[2];
    const float* W1  = (const float*)d_in[3];
    const float* b1  = (const float*)d_in[4];
    const float* W2  = (const float*)d_in[5];
    const float* b2  = (const float*)d_in[6];
    const float* W3  = (const float*)d_in[7];
    const float* b3  = (const float*)d_in[8];
    const float* Wf1 = (const float*)d_in[9];
    const float* bf1 = (const float*)d_in[10];
    const float* Wf2 = (const float*)d_in[11];
    const float* bf2 = (const float*)d_in[12];
    float* out = (float*)d_out;

    // ---- workspace layout ----------------------------------------------
    char* base = (char*)d_ws;
    size_t off = 0;
    auto alloc = [&](size_t bytes) {
        size_t o = off; off = (off + bytes + 255) & ~(size_t)255; return o;
    };
    const size_t o_wpw  = alloc((size_t)NCH * 128 * 2);
    const size_t o_wct1 = alloc((size_t)NCH * 768 * 2);
    const size_t o_wct2 = alloc((size_t)NCH * 768 * 2);
    const size_t o_wct3 = alloc((size_t)NCH * 768 * 2);
    const size_t o_wf1h = alloc((size_t)F1_ * FCK * 2);
    const size_t fixed  = off;

    int CB = 0;
    const int cand[5] = {2048, 1024, 512, 256, 128};
    for (int i = 0; i < 5; ++i) {
        size_t c = (size_t)cand[i];
        size_t need = fixed
            + (((size_t)SPLIT * c * F1_ * 4 + 255) & ~(size_t)255)   // part
            + ((c * (size_t)L0_ * NCH * 2 + 255) & ~(size_t)255)     // buf0
            + ((c * (size_t)L1_ * NCH * 2 + 255) & ~(size_t)255);    // buf1
        if (need <= ws_size) { CB = cand[i]; break; }
    }
    if (CB == 0) return;
    const int nchunk = B_SZ / CB;

    const size_t o_part = alloc((size_t)SPLIT * CB * F1_ * 4);
    const size_t o_buf0 = alloc((size_t)CB * L0_ * NCH * 2);
    const size_t o_buf1 = alloc((size_t)CB * L1_ * NCH * 2);

    f16*   wpw  = (f16*)(base + o_wpw);
    f16*   wct1 = (f16*)(base + o_wct1);
    f16*   wct2 = (f16*)(base + o_wct2);
    f16*   wct3 = (f16*)(base + o_wct3);
    f16*   wf1h = (f16*)(base + o_wf1h);
    float* part = (float*)(base + o_part);
    f16*   buf0 = (f16*)(base + o_buf0);
    f16*   buf1 = (f16*)(base + o_buf1);

    // ---- preps ---------------------------------------------------------
    prep_w<<<2432, 256, 0, stream>>>(Wp, W1, W2, W3, wpw, wct1, wct2, wct3);
    prep_wf1k<<<F1_, 256, 0, stream>>>(Wf1, wf1h);

    // ---- chunked pipeline ----------------------------------------------
    for (int c = 0; c < nchunk; ++c) {
        const size_t b0 = (size_t)c * CB;
        // pointwise as K=128 GEMM (2 BK-64 steps), fp32 x staged in-kernel
        convk<2, 4, 16, 128, 128, 128, L0_, true><<<CB, 256, 0, stream>>>(
            nullptr, 0, x + b0 * 8192, wpw, bp, buf0);
        convk<12, 8, 32, 256, 130, L0_, L1_, false><<<CB, 256, 0, stream>>>(
            buf0, (long)L0_ * NCH, nullptr, wct1, b1, buf1);
        convk<12, 8, 32, 256, 130, L1_, L2_, false><<<CB, 256, 0, stream>>>(
            buf1, (long)L1_ * NCH, nullptr, wct2, b2, buf0);
        convk<12, 8, 32, 256, 130, L2_, L3_, false><<<CB, 256, 0, stream>>>(
            buf0, (long)L2_ * NCH, nullptr, wct3, b3, buf1);
        // conv3 output [l][co] IS the FC1 A layout (wf1h K-permuted at prep)
        fc1k<<<dim3(CB / 128, 2, SPLIT), 512, 0, stream>>>(buf1, wf1h, part, CB);
        fcout<<<CB, 512, 0, stream>>>(part, bf1, Wf2, bf2, out + b0, CB);
    }
}